// Round 4
// baseline (490.501 us; speedup 1.0000x reference)
//
#include <hip/hip_runtime.h>

#define EF 16      // EDGE_FEAT
#define EH 32      // EDGE_HID
#define NF 128     // NODE_FEAT
#define K1 160     // EH + NF
#define HS 168     // LDS hA row stride (ushorts)
#define H2S 136    // LDS hB row stride (ushorts)

typedef __attribute__((ext_vector_type(8))) short bf16x8;
typedef __attribute__((ext_vector_type(4))) float f32x4;

__device__ __forceinline__ unsigned short f2b(float f) {  // fp32 -> bf16 RNE
  unsigned u = __float_as_uint(f);
  u += 0x7FFFu + ((u >> 16) & 1u);
  return (unsigned short)(u >> 16);
}
__device__ __forceinline__ unsigned pack2b(float a, float b) {  // [b|a] packed bf16
  return (unsigned)f2b(a) | ((unsigned)f2b(b) << 16);
}

// ---------------- init: zero counts + build bf16-transposed weights ----------------
__global__ void k_init(unsigned* __restrict__ cnt, int n,
                       const float* __restrict__ W1, const float* __restrict__ W2,
                       unsigned short* __restrict__ w1t, unsigned short* __restrict__ w2t) {
  int i = blockIdx.x * blockDim.x + threadIdx.x;
  if (i < n) cnt[i] = 0u;
  if (i < K1 * NF) {                    // w1t[n][k] = W1[k][n]
    int nn = i / K1, k = i % K1;
    w1t[i] = f2b(W1[k * NF + nn]);
  } else if (i < K1 * NF + NF * NF) {   // w2t[n][k] = W2[k][n]
    int j = i - K1 * NF;
    int nn = j / NF, k = j % NF;
    w2t[j] = f2b(W2[k * NF + nn]);
  }
}

// histogram; atomic return value doubles as the edge's within-node rank
__global__ void k_hist(const int* __restrict__ dst, unsigned* __restrict__ cnt,
                       unsigned* __restrict__ rank, int n_edges) {
  int e = blockIdx.x * blockDim.x + threadIdx.x;
  if (e >= n_edges) return;
  rank[e] = atomicAdd(&cnt[dst[e]], 1u);
}

// block scans 1024 elems (256 thr x 4); exclusive partials + block sum
__global__ void k_scan1(const unsigned* __restrict__ cnt, unsigned* __restrict__ offs,
                        unsigned* __restrict__ bsum, int n) {
  __shared__ unsigned ts[256];
  int t = threadIdx.x;
  int base = blockIdx.x * 1024 + t * 4;
  unsigned v[4];
#pragma unroll
  for (int i = 0; i < 4; ++i) { int idx = base + i; v[i] = (idx < n) ? cnt[idx] : 0u; }
  unsigned run = 0;
#pragma unroll
  for (int i = 0; i < 4; ++i) { unsigned x = v[i]; v[i] = run; run += x; }
  ts[t] = run;
  __syncthreads();
  for (int off = 1; off < 256; off <<= 1) {
    unsigned add = (t >= off) ? ts[t - off] : 0u;
    __syncthreads();
    ts[t] += add;
    __syncthreads();
  }
  unsigned texcl = (t > 0) ? ts[t - 1] : 0u;
  if (t == 255) bsum[blockIdx.x] = ts[255];
#pragma unroll
  for (int i = 0; i < 4; ++i) { int idx = base + i; if (idx < n) offs[idx] = v[i] + texcl; }
}

// fused: each block redundantly scans bsum in LDS, then offsets its 1024 elems
__global__ void k_scan3(unsigned* __restrict__ offs, const unsigned* __restrict__ bsum,
                        int n, int nb) {
  __shared__ unsigned ts[256];
  int t = threadIdx.x;
  ts[t] = (t < nb) ? bsum[t] : 0u;
  __syncthreads();
  for (int off = 1; off < 256; off <<= 1) {
    unsigned add = (t >= off) ? ts[t - off] : 0u;
    __syncthreads();
    ts[t] += add;
    __syncthreads();
  }
  unsigned add = (blockIdx.x > 0) ? ts[blockIdx.x - 1] : 0u;
  int base = blockIdx.x * 1024 + t * 4;
#pragma unroll
  for (int i = 0; i < 4; ++i) { int idx = base + i; if (idx < n) offs[idx] += add; }
}

// XCD-partitioned, atomic-free PRODUCT scatter. blockIdx = chunk*8 + xcdSlot.
// Streams a contiguous edge window; for the ~1/8 of edges whose dst falls in this
// XCD's node slice, reads the 64B efeat row (ADDRESSES MONOTONICALLY INCREASING --
// no random HBM row activations; 128B lines shared across the 8 concurrent XCD
// sweeps via L3), premultiplies by ex, writes one 32B bf16 record + 4B exs.
// Writes land in a 6.4MB/XCD slot range -> mostly L2-resident, full-line writebacks
// (rounds 1/2 showed non-partitioned 32B scatter costs 100MB of writes).
// slot = offs[d] + rank[e] is globally collision-free.
__global__ __launch_bounds__(256) void k_prod(
    const int* __restrict__ dst, const unsigned* __restrict__ rank,
    const float* __restrict__ logits, const unsigned* __restrict__ offs,
    const float* __restrict__ efeat,
    unsigned* __restrict__ prodb, float* __restrict__ exs,
    int n_edges, int nps, int n_nodes, int chunks) {
  int xcd = blockIdx.x & 7;
  int chunk = blockIdx.x >> 3;
  int lo = xcd * nps;
  int hi = min(lo + nps, n_nodes);
  int per = (n_edges + chunks - 1) / chunks;
  int e0 = chunk * per;
  int e1 = min(e0 + per, n_edges);
  for (int e = e0 + (int)threadIdx.x; e < e1; e += 256) {
    int d = dst[e];
    if (d >= lo && d < hi) {
      unsigned slot = offs[d] + rank[e];
      float ex = __expf(logits[e]);   // no max-shift: logits ~N(0,1), fp32-safe
      exs[slot] = ex;
      const float4* fp = (const float4*)(efeat + (size_t)e * EF);
      float4 v0 = fp[0], v1 = fp[1], v2 = fp[2], v3 = fp[3];
      uint4 o0, o1;
      o0.x = pack2b(ex * v0.x, ex * v0.y);
      o0.y = pack2b(ex * v0.z, ex * v0.w);
      o0.z = pack2b(ex * v1.x, ex * v1.y);
      o0.w = pack2b(ex * v1.z, ex * v1.w);
      o1.x = pack2b(ex * v2.x, ex * v2.y);
      o1.y = pack2b(ex * v2.z, ex * v2.w);
      o1.z = pack2b(ex * v3.x, ex * v3.y);
      o1.w = pack2b(ex * v3.z, ex * v3.w);
      uint4* pp = (uint4*)(prodb + (size_t)slot * 8);
      pp[0] = o0;
      pp[1] = o1;
    }
  }
}

// ---------------- per-node STREAMING segmented sum + context (16->32 + ELU) --------
// one wave per node; lane = (record-group rg = lane>>3) x (u32 col c = lane&7);
// each wave-batch reads 8 records x 32B = 256B contiguous. 2x unrolled (16 records
// in flight, matches avg degree). Node mapping XCD-swizzled to match k_prod's
// partition, so reads hit the dirty prodb lines still resident in this XCD's L2.
__global__ __launch_bounds__(256) void k_gather(
    const unsigned* __restrict__ prodb, const float* __restrict__ exs,
    const unsigned* __restrict__ cnt, const unsigned* __restrict__ offs,
    const float* __restrict__ W_et, const float* __restrict__ b_et,
    unsigned short* __restrict__ ctxb, int nps, int n_nodes) {
  int xcd = blockIdx.x & 7;
  int idx = blockIdx.x >> 3;
  int node = xcd * nps + (idx << 2) + (int)(threadIdx.x >> 6);
  int node_end = min(xcd * nps + nps, n_nodes);
  if (node >= node_end) return;
  int lane = threadIdx.x & 63;
  unsigned start = offs[node];
  unsigned deg = cnt[node];
  int rg = lane >> 3, c = lane & 7;
  float a0 = 0.0f, a1 = 0.0f;   // feature sums for features 2c, 2c+1
  unsigned i = rg;
  for (; i + 8 < deg; i += 16) {
    unsigned p = prodb[(size_t)(start + i) * 8 + c];
    unsigned q = prodb[(size_t)(start + i + 8) * 8 + c];
    a0 += __uint_as_float(p << 16) + __uint_as_float(q << 16);
    a1 += __uint_as_float(p & 0xFFFF0000u) + __uint_as_float(q & 0xFFFF0000u);
  }
  for (; i < deg; i += 8) {
    unsigned p = prodb[(size_t)(start + i) * 8 + c];
    a0 += __uint_as_float(p << 16);
    a1 += __uint_as_float(p & 0xFFFF0000u);
  }
  a0 += __shfl_xor(a0, 8);  a1 += __shfl_xor(a1, 8);
  a0 += __shfl_xor(a0, 16); a1 += __shfl_xor(a1, 16);
  a0 += __shfl_xor(a0, 32); a1 += __shfl_xor(a1, 32);
  float dsum = 0.0f;
  for (unsigned k = lane; k < deg; k += 64) dsum += exs[start + k];
  dsum += __shfl_xor(dsum, 1);
  dsum += __shfl_xor(dsum, 2);
  dsum += __shfl_xor(dsum, 4);
  dsum += __shfl_xor(dsum, 8);
  dsum += __shfl_xor(dsum, 16);
  dsum += __shfl_xor(dsum, 32);
  float inv = (deg > 0) ? 1.0f / dsum : 0.0f;
  float S = (deg > 0) ? 1.0f : 0.0f;
  int j = lane & 31;
  float acc = 0.0f;
#pragma unroll
  for (int k = 0; k < 16; ++k) {
    float sk = (k & 1) ? __shfl(a1, k >> 1) : __shfl(a0, k >> 1);
    acc += sk * W_et[k * EH + j];
  }
  float cv = acc * inv + S * b_et[j];
  float ctxv = (cv > 0.0f) ? cv : (__expf(cv) - 1.0f);
  if (lane < 32) ctxb[(size_t)node * EH + lane] = f2b(ctxv);
}

// ---------------- per-node 2-layer MLP via bf16 MFMA (unchanged) ----------------
// 64 nodes/block, 4 waves; wave w owns node rows [w*16, w*16+16), full 128 cols.
// A layout (m89): A[m=lane&15][k=(lane>>4)*8+j]; C/D: row=(lane>>4)*4+reg, col=lane&15.
__global__ __launch_bounds__(256) void k_node(
    const unsigned short* __restrict__ ctxb, const float* __restrict__ nf,
    const unsigned short* __restrict__ w1t, const unsigned short* __restrict__ w2t,
    const float* __restrict__ b1, const float* __restrict__ b2,
    float* __restrict__ out, int n_nodes) {
  __shared__ __align__(16) unsigned short hA[64 * HS];
  __shared__ __align__(16) unsigned short hB[64 * H2S];
  const int t = threadIdx.x;
  const int w = t >> 6, lane = t & 63;
  const int m = lane & 15, q = lane >> 4;
  int n0 = blockIdx.x * 64;
  if (n0 + 64 > n_nodes) n0 = n_nodes - 64;  // tail overlap: identical rewrites, benign

  // stage ctx (bf16 passthrough): 64x32, 8 ushorts/thread
  {
    int node = t >> 2, j = (t & 3) * 8;
    *(uint4*)&hA[node * HS + j] = *(const uint4*)&ctxb[(size_t)(n0 + node) * EH + j];
  }
  // stage node_feats fp32 -> bf16: 64x128, 8x float4/thread
#pragma unroll
  for (int i = 0; i < 8; ++i) {
    int idx = t + 256 * i;
    int node = idx >> 5, j = (idx & 31) * 4;
    float4 v = *(const float4*)&nf[(size_t)(n0 + node) * NF + j];
    unsigned short r[4] = {f2b(v.x), f2b(v.y), f2b(v.z), f2b(v.w)};
    *(uint2*)&hA[node * HS + EH + j] = *(const uint2*)r;
  }
  __syncthreads();

  const int mr = w * 16;
  f32x4 acc[8];
#pragma unroll
  for (int nt = 0; nt < 8; ++nt) acc[nt] = (f32x4){0.f, 0.f, 0.f, 0.f};
  for (int ks = 0; ks < 5; ++ks) {
    bf16x8 a = *(const bf16x8*)&hA[(mr + m) * HS + ks * 32 + q * 8];
#pragma unroll
    for (int nt = 0; nt < 8; ++nt) {
      bf16x8 b = *(const bf16x8*)&w1t[(size_t)(nt * 16 + m) * K1 + ks * 32 + q * 8];
      acc[nt] = __builtin_amdgcn_mfma_f32_16x16x32_bf16(a, b, acc[nt], 0, 0, 0);
    }
  }
  // epilogue 1: bias + relu -> hB (bf16), wave-private rows
#pragma unroll
  for (int nt = 0; nt < 8; ++nt) {
    float bb = b1[nt * 16 + m];
#pragma unroll
    for (int r = 0; r < 4; ++r) {
      float v = fmaxf(acc[nt][r] + bb, 0.0f);
      hB[(mr + q * 4 + r) * H2S + nt * 16 + m] = f2b(v);
    }
  }
  __syncthreads();

  f32x4 ac2[8];
#pragma unroll
  for (int nt = 0; nt < 8; ++nt) ac2[nt] = (f32x4){0.f, 0.f, 0.f, 0.f};
  for (int ks = 0; ks < 4; ++ks) {
    bf16x8 a = *(const bf16x8*)&hB[(mr + m) * H2S + ks * 32 + q * 8];
#pragma unroll
    for (int nt = 0; nt < 8; ++nt) {
      bf16x8 b = *(const bf16x8*)&w2t[(size_t)(nt * 16 + m) * NF + ks * 32 + q * 8];
      ac2[nt] = __builtin_amdgcn_mfma_f32_16x16x32_bf16(a, b, ac2[nt], 0, 0, 0);
    }
  }
#pragma unroll
  for (int nt = 0; nt < 8; ++nt) {
    float bb = b2[nt * 16 + m];
#pragma unroll
    for (int r = 0; r < 4; ++r) {
      out[(size_t)(n0 + mr + q * 4 + r) * NF + nt * 16 + m] = fmaxf(ac2[nt][r] + bb, 0.0f);
    }
  }
}

extern "C" void kernel_launch(void* const* d_in, const int* in_sizes, int n_in,
                              void* d_out, int out_size, void* d_ws, size_t ws_size,
                              hipStream_t stream) {
  const float* edge_logits = (const float*)d_in[0];
  const float* edge_feats  = (const float*)d_in[1];
  const float* node_feats  = (const float*)d_in[2];
  const int*   dst         = (const int*)d_in[3];
  const float* W_et        = (const float*)d_in[4];
  const float* b_et        = (const float*)d_in[5];
  const float* W1          = (const float*)d_in[6];
  const float* b1          = (const float*)d_in[7];
  const float* W2          = (const float*)d_in[8];
  const float* b2          = (const float*)d_in[9];
  float* out = (float*)d_out;

  const int E = in_sizes[0];          // 1,600,000
  const int n = in_sizes[2] / NF;     // 100,000

  // ws layout (u32 units)
  unsigned* cnt  = (unsigned*)d_ws;               // n
  unsigned* offs = cnt + n;                       // n
  unsigned* bsum = offs + n;                      // 256
  unsigned* rank = bsum + 256;                    // E
  float*    exs  = (float*)(rank + E);            // E
  unsigned* prodb = (unsigned*)(((uintptr_t)(exs + E) + 255) & ~(uintptr_t)255);  // E*8 u32, line-aligned
  unsigned short* ctxb = (unsigned short*)(prodb + (size_t)E * 8);  // n*32 bf16
  unsigned short* w1t  = ctxb + (size_t)n * EH;   // 160*128 bf16
  unsigned short* w2t  = w1t + NF * K1;           // 128*128 bf16

  const int thr = 256;
  const int nscan = (n + 1023) / 1024;
  const int chunks = 256;             // k_prod grid = chunks * 8 XCD slots
  const int nps = (n + 7) >> 3;       // nodes per XCD slice (shared by k_prod/k_gather)

  k_init<<<(n + thr - 1) / thr, thr, 0, stream>>>(cnt, n, W1, W2, w1t, w2t);
  k_hist<<<(E + thr - 1) / thr, thr, 0, stream>>>(dst, cnt, rank, E);
  k_scan1<<<nscan, 256, 0, stream>>>(cnt, offs, bsum, n);
  k_scan3<<<nscan, 256, 0, stream>>>(offs, bsum, n, nscan);
  k_prod<<<chunks * 8, 256, 0, stream>>>(dst, rank, edge_logits, offs, edge_feats,
                                         prodb, exs, E, nps, n, chunks);
  const int gblocks = 8 * ((nps + 3) >> 2);   // 4 nodes (waves) per block, XCD-sliced
  k_gather<<<gblocks, 256, 0, stream>>>(prodb, exs, cnt, offs, W_et, b_et, ctxb, nps, n);
  k_node<<<(n + 63) / 64, 256, 0, stream>>>(ctxb, node_feats, w1t, w2t, b1, b2, out, n);
}

// Round 5
// 402.984 us; speedup vs baseline: 1.2172x; 1.2172x over previous
//
#include <hip/hip_runtime.h>

#define EF 16      // EDGE_FEAT
#define EH 32      // EDGE_HID
#define NF 128     // NODE_FEAT
#define K1 160     // EH + NF
#define HS 168     // LDS hA row stride (ushorts)
#define H2S 136    // LDS hB row stride (ushorts)

typedef __attribute__((ext_vector_type(8))) short bf16x8;
typedef __attribute__((ext_vector_type(4))) float f32x4;

__device__ __forceinline__ unsigned short f2b(float f) {  // fp32 -> bf16 RNE
  unsigned u = __float_as_uint(f);
  u += 0x7FFFu + ((u >> 16) & 1u);
  return (unsigned short)(u >> 16);
}

// ---- init: zero ctx/denom accumulators + build bf16-transposed weights ----
// (must re-zero every launch: atomics accumulate, and ws may be re-poisoned)
__global__ void k_init(float* __restrict__ ctx, float* __restrict__ denom, int n,
                       const float* __restrict__ W1, const float* __restrict__ W2,
                       unsigned short* __restrict__ w1t, unsigned short* __restrict__ w2t) {
  int i = blockIdx.x * blockDim.x + threadIdx.x;
  if (i < n * EF) ctx[i] = 0.0f;
  if (i < n) denom[i] = 0.0f;
  if (i < K1 * NF) {                    // w1t[nn][k] = W1[k][nn]
    int nn = i / K1, k = i % K1;
    w1t[i] = f2b(W1[k * NF + nn]);
  } else if (i < K1 * NF + NF * NF) {   // w2t[nn][k] = W2[k][nn]
    int j = i - K1 * NF;
    int nn = j / NF, k = j % NF;
    w2t[j] = f2b(W2[k * NF + nn]);
  }
}

// ---- single streaming pass over edges: segmented sum via HW fp32 atomics ----
// 16-lane group per edge: lanes read the 64B efeat row fully coalesced (a wave
// covers 256B of efeat per step); each lane does ONE atomicAdd into the 6.4MB
// ctx accumulator (addresses uniformly spread -> negligible same-address
// contention, unlike k_hist's 400KB counter array). No sort, no perm, no prodb.
// Atomics are fire-and-forget (no return value) -> no dependent stalls; TLP
// (32k groups in flight) hides the memory-side atomic latency.
__global__ __launch_bounds__(256) void k_edge(
    const int* __restrict__ dst, const float* __restrict__ logits,
    const float* __restrict__ efeat,
    float* __restrict__ ctx, float* __restrict__ denom, int n_edges) {
  int gid = (int)((blockIdx.x * blockDim.x + threadIdx.x) >> 4);
  int c = threadIdx.x & 15;
  int ngroups = (int)((gridDim.x * blockDim.x) >> 4);
#pragma unroll 2
  for (int e = gid; e < n_edges; e += ngroups) {
    int d = dst[e];                        // broadcast within group (1 line/wave)
    float ex = __expf(logits[e]);          // no max-shift: logits ~N(0,1), fp32-safe
    float f = efeat[(size_t)e * EF + c];   // 64B row, coalesced across the wave
    unsafeAtomicAdd(&ctx[(size_t)d * EF + c], ex * f);
    if (c == 0) unsafeAtomicAdd(&denom[d], ex);
  }
}

// ---- per-node 2-layer MLP via bf16 MFMA, with fused context finisher ----
// Staging now computes the 16->32 GEMV + normalize + ELU from the fp32 ctx
// accumulators directly into hA (replaces the old ctxb intermediate + k_gather):
// c_j = (sum_k ctx_k * W_et[k][j]) / denom + b_et[j]   (deg>0; sum(alpha)=1)
//     = 0 for empty nodes (denom==0 -> elu(0)=0, matches reference).
// 64 nodes/block, 4 waves; wave w owns node rows [w*16, w*16+16), full 128 cols.
// A layout (m89): A[m=lane&15][k=(lane>>4)*8+j]; C/D: row=(lane>>4)*4+reg, col=lane&15.
__global__ __launch_bounds__(256) void k_node(
    const float* __restrict__ ctx, const float* __restrict__ denom,
    const float* __restrict__ W_et, const float* __restrict__ b_et,
    const float* __restrict__ nf,
    const unsigned short* __restrict__ w1t, const unsigned short* __restrict__ w2t,
    const float* __restrict__ b1, const float* __restrict__ b2,
    float* __restrict__ out, int n_nodes) {
  __shared__ __align__(16) unsigned short hA[64 * HS];
  __shared__ __align__(16) unsigned short hB[64 * H2S];
  const int t = threadIdx.x;
  const int w = t >> 6, lane = t & 63;
  const int m = lane & 15, q = lane >> 4;
  int n0 = blockIdx.x * 64;
  if (n0 + 64 > n_nodes) n0 = n_nodes - 64;  // tail overlap: identical rewrites, benign

  // stage context: GEMV 16->32 + normalize + bias + ELU -> bf16. 8 outputs/thread.
  {
    int node = t >> 2, jg = (t & 3) * 8;
    float den = denom[n0 + node];
    float inv = (den > 0.0f) ? 1.0f / den : 0.0f;
    float S = (den > 0.0f) ? 1.0f : 0.0f;
    const float* cr = &ctx[(size_t)(n0 + node) * EF];
    unsigned short r[8];
#pragma unroll
    for (int jj = 0; jj < 8; ++jj) {
      int j = jg + jj;
      float acc = 0.0f;
#pragma unroll
      for (int k = 0; k < EF; ++k) acc += cr[k] * W_et[k * EH + j];
      float cv = acc * inv + S * b_et[j];
      float ctxv = (cv > 0.0f) ? cv : (__expf(cv) - 1.0f);
      r[jj] = f2b(ctxv);
    }
    *(uint4*)&hA[node * HS + jg] = *(const uint4*)r;
  }
  // stage node_feats fp32 -> bf16: 64x128, 8x float4/thread
#pragma unroll
  for (int i = 0; i < 8; ++i) {
    int idx = t + 256 * i;
    int node = idx >> 5, j = (idx & 31) * 4;
    float4 v = *(const float4*)&nf[(size_t)(n0 + node) * NF + j];
    unsigned short r[4] = {f2b(v.x), f2b(v.y), f2b(v.z), f2b(v.w)};
    *(uint2*)&hA[node * HS + EH + j] = *(const uint2*)r;
  }
  __syncthreads();

  const int mr = w * 16;
  f32x4 acc[8];
#pragma unroll
  for (int nt = 0; nt < 8; ++nt) acc[nt] = (f32x4){0.f, 0.f, 0.f, 0.f};
  for (int ks = 0; ks < 5; ++ks) {
    bf16x8 a = *(const bf16x8*)&hA[(mr + m) * HS + ks * 32 + q * 8];
#pragma unroll
    for (int nt = 0; nt < 8; ++nt) {
      bf16x8 b = *(const bf16x8*)&w1t[(size_t)(nt * 16 + m) * K1 + ks * 32 + q * 8];
      acc[nt] = __builtin_amdgcn_mfma_f32_16x16x32_bf16(a, b, acc[nt], 0, 0, 0);
    }
  }
  // epilogue 1: bias + relu -> hB (bf16), wave-private rows
#pragma unroll
  for (int nt = 0; nt < 8; ++nt) {
    float bb = b1[nt * 16 + m];
#pragma unroll
    for (int r = 0; r < 4; ++r) {
      float v = fmaxf(acc[nt][r] + bb, 0.0f);
      hB[(mr + q * 4 + r) * H2S + nt * 16 + m] = f2b(v);
    }
  }
  __syncthreads();

  f32x4 ac2[8];
#pragma unroll
  for (int nt = 0; nt < 8; ++nt) ac2[nt] = (f32x4){0.f, 0.f, 0.f, 0.f};
  for (int ks = 0; ks < 4; ++ks) {
    bf16x8 a = *(const bf16x8*)&hB[(mr + m) * H2S + ks * 32 + q * 8];
#pragma unroll
    for (int nt = 0; nt < 8; ++nt) {
      bf16x8 b = *(const bf16x8*)&w2t[(size_t)(nt * 16 + m) * NF + ks * 32 + q * 8];
      ac2[nt] = __builtin_amdgcn_mfma_f32_16x16x32_bf16(a, b, ac2[nt], 0, 0, 0);
    }
  }
#pragma unroll
  for (int nt = 0; nt < 8; ++nt) {
    float bb = b2[nt * 16 + m];
#pragma unroll
    for (int r = 0; r < 4; ++r) {
      out[(size_t)(n0 + mr + q * 4 + r) * NF + nt * 16 + m] = fmaxf(ac2[nt][r] + bb, 0.0f);
    }
  }
}

extern "C" void kernel_launch(void* const* d_in, const int* in_sizes, int n_in,
                              void* d_out, int out_size, void* d_ws, size_t ws_size,
                              hipStream_t stream) {
  const float* edge_logits = (const float*)d_in[0];
  const float* edge_feats  = (const float*)d_in[1];
  const float* node_feats  = (const float*)d_in[2];
  const int*   dst         = (const int*)d_in[3];
  const float* W_et        = (const float*)d_in[4];
  const float* b_et        = (const float*)d_in[5];
  const float* W1          = (const float*)d_in[6];
  const float* b1          = (const float*)d_in[7];
  const float* W2          = (const float*)d_in[8];
  const float* b2          = (const float*)d_in[9];
  float* out = (float*)d_out;

  const int E = in_sizes[0];          // 1,600,000
  const int n = in_sizes[2] / NF;     // 100,000

  // ws layout
  float* ctx   = (float*)d_ws;                    // n*16 f32 accumulators
  float* denom = ctx + (size_t)n * EF;            // n f32
  unsigned short* w1t = (unsigned short*)(denom + n);  // 160*128 bf16
  unsigned short* w2t = w1t + NF * K1;                 // 128*128 bf16

  const int thr = 256;
  const int initN = n * EF;                            // covers ctx, denom, weights

  k_init<<<(initN + thr - 1) / thr, thr, 0, stream>>>(ctx, denom, n, W1, W2, w1t, w2t);
  k_edge<<<2048, thr, 0, stream>>>(dst, edge_logits, edge_feats, ctx, denom, E);
  k_node<<<(n + 63) / 64, 256, 0, stream>>>(ctx, denom, W_et, b_et, node_feats,
                                            w1t, w2t, b1, b2, out, n);
}

// Round 6
// 392.451 us; speedup vs baseline: 1.2498x; 1.0268x over previous
//
#include <hip/hip_runtime.h>

#define EF 16      // EDGE_FEAT
#define EH 32      // EDGE_HID
#define NF 128     // NODE_FEAT
#define K1 160     // EH + NF
#define HS 168     // LDS hA row stride (ushorts)
#define H2S 136    // LDS hB row stride (ushorts)

typedef __attribute__((ext_vector_type(8))) short bf16x8;
typedef __attribute__((ext_vector_type(4))) float f32x4;

__device__ __forceinline__ unsigned short f2b(float f) {  // fp32 -> bf16 RNE
  unsigned u = __float_as_uint(f);
  u += 0x7FFFu + ((u >> 16) & 1u);
  return (unsigned short)(u >> 16);
}
__device__ __forceinline__ unsigned pack2b(float a, float b) {  // [b|a] packed bf16
  return (unsigned)f2b(a) | ((unsigned)f2b(b) << 16);
}
// HW packed bf16x2 atomic add (gfx950 global_atomic_pk_add_bf16), fire-and-forget.
// Inline asm: deterministic codegen, no dependence on unsafeAtomicAdd overload set.
__device__ __forceinline__ void atom_pk_bf16(unsigned* addr, unsigned val) {
  asm volatile("global_atomic_pk_add_bf16 %0, %1, off" :: "v"(addr), "v"(val) : "memory");
}

// ---- init: zero bf16 ctx accumulators + denom + build bf16-transposed weights ----
__global__ void k_init(unsigned* __restrict__ ctx, float* __restrict__ denom, int n,
                       const float* __restrict__ W1, const float* __restrict__ W2,
                       unsigned short* __restrict__ w1t, unsigned short* __restrict__ w2t) {
  int i = blockIdx.x * blockDim.x + threadIdx.x;
  if (i < n * 8) ctx[i] = 0u;           // n x 16 bf16 = n x 8 u32
  if (i < n) denom[i] = 0.0f;
  if (i < K1 * NF) {                    // w1t[nn][k] = W1[k][nn]
    int nn = i / K1, k = i % K1;
    w1t[i] = f2b(W1[k * NF + nn]);
  } else if (i < K1 * NF + NF * NF) {   // w2t[nn][k] = W2[k][nn]
    int j = i - K1 * NF;
    int nn = j / NF, k = j % NF;
    w2t[j] = f2b(W2[k * NF + nn]);
  }
}

// ---- single streaming pass over edges: segmented sum via packed-bf16 HW atomics ----
// 8 lanes per edge; each lane owns feature pair (2c, 2c+1): loads 8B of the 64B
// efeat row (fully coalesced across the wave: 8 edges x 64B = 512B/step) and issues
// ONE global_atomic_pk_add_bf16 into the 3.2MB bf16 ctx accumulator.
// r5 measured the atomic-op-rate ceiling (~155G lane-ops/s): 27.2M ops -> 175us.
// This halves ctx ops (25.6M -> 12.8M packed). denom stays fp32 (1 op/edge).
// bf16 accumulation error (~0.0014 on context after /denom) << bf16 MFMA error.
__global__ __launch_bounds__(256) void k_edge(
    const int* __restrict__ dst, const float* __restrict__ logits,
    const float* __restrict__ efeat,
    unsigned* __restrict__ ctx, float* __restrict__ denom, int n_edges) {
  int gid = (int)((blockIdx.x * blockDim.x + threadIdx.x) >> 3);
  int c = threadIdx.x & 7;              // bf16-pair index (features 2c, 2c+1)
  int ngroups = (int)((gridDim.x * blockDim.x) >> 3);
#pragma unroll 2
  for (int e = gid; e < n_edges; e += ngroups) {
    int d = dst[e];                     // broadcast within group
    float ex = __expf(logits[e]);       // no max-shift: logits ~N(0,1), fp32-safe
    float2 f = *(const float2*)&efeat[(size_t)e * EF + c * 2];
    atom_pk_bf16(&ctx[(size_t)d * 8 + c], pack2b(ex * f.x, ex * f.y));
    if (c == 0) unsafeAtomicAdd(&denom[d], ex);
  }
}

// ---- per-node 2-layer MLP via bf16 MFMA, with fused context finisher ----
// Staging computes the 16->32 GEMV + normalize + bias + ELU from the bf16 ctx
// accumulators directly into hA:
// c_j = (sum_k ctx_k * W_et[k][j]) / denom + b_et[j]  (denom==0 -> 0 -> elu(0)=0).
// 64 nodes/block, 4 waves; wave w owns node rows [w*16, w*16+16), full 128 cols.
// A layout (m89): A[m=lane&15][k=(lane>>4)*8+j]; C/D: row=(lane>>4)*4+reg, col=lane&15.
__global__ __launch_bounds__(256) void k_node(
    const unsigned short* __restrict__ ctxb, const float* __restrict__ denom,
    const float* __restrict__ W_et, const float* __restrict__ b_et,
    const float* __restrict__ nf,
    const unsigned short* __restrict__ w1t, const unsigned short* __restrict__ w2t,
    const float* __restrict__ b1, const float* __restrict__ b2,
    float* __restrict__ out, int n_nodes) {
  __shared__ __align__(16) unsigned short hA[64 * HS];
  __shared__ __align__(16) unsigned short hB[64 * H2S];
  const int t = threadIdx.x;
  const int w = t >> 6, lane = t & 63;
  const int m = lane & 15, q = lane >> 4;
  int n0 = blockIdx.x * 64;
  if (n0 + 64 > n_nodes) n0 = n_nodes - 64;  // tail overlap: identical rewrites, benign

  // stage context: GEMV 16->32 + normalize + bias + ELU -> bf16. 8 outputs/thread.
  {
    int node = t >> 2, jg = (t & 3) * 8;
    float den = denom[n0 + node];
    float inv = (den > 0.0f) ? 1.0f / den : 0.0f;
    float S = (den > 0.0f) ? 1.0f : 0.0f;
    const unsigned short* cr = &ctxb[(size_t)(n0 + node) * EF];
    float cf[EF];
#pragma unroll
    for (int k = 0; k < EF; ++k) cf[k] = __uint_as_float((unsigned)cr[k] << 16);
    unsigned short r[8];
#pragma unroll
    for (int jj = 0; jj < 8; ++jj) {
      int j = jg + jj;
      float acc = 0.0f;
#pragma unroll
      for (int k = 0; k < EF; ++k) acc += cf[k] * W_et[k * EH + j];
      float cv = acc * inv + S * b_et[j];
      float ctxv = (cv > 0.0f) ? cv : (__expf(cv) - 1.0f);
      r[jj] = f2b(ctxv);
    }
    *(uint4*)&hA[node * HS + jg] = *(const uint4*)r;
  }
  // stage node_feats fp32 -> bf16: 64x128, 8x float4/thread
#pragma unroll
  for (int i = 0; i < 8; ++i) {
    int idx = t + 256 * i;
    int node = idx >> 5, j = (idx & 31) * 4;
    float4 v = *(const float4*)&nf[(size_t)(n0 + node) * NF + j];
    unsigned short r[4] = {f2b(v.x), f2b(v.y), f2b(v.z), f2b(v.w)};
    *(uint2*)&hA[node * HS + EH + j] = *(const uint2*)r;
  }
  __syncthreads();

  const int mr = w * 16;
  f32x4 acc[8];
#pragma unroll
  for (int nt = 0; nt < 8; ++nt) acc[nt] = (f32x4){0.f, 0.f, 0.f, 0.f};
  for (int ks = 0; ks < 5; ++ks) {
    bf16x8 a = *(const bf16x8*)&hA[(mr + m) * HS + ks * 32 + q * 8];
#pragma unroll
    for (int nt = 0; nt < 8; ++nt) {
      bf16x8 b = *(const bf16x8*)&w1t[(size_t)(nt * 16 + m) * K1 + ks * 32 + q * 8];
      acc[nt] = __builtin_amdgcn_mfma_f32_16x16x32_bf16(a, b, acc[nt], 0, 0, 0);
    }
  }
  // epilogue 1: bias + relu -> hB (bf16), wave-private rows
#pragma unroll
  for (int nt = 0; nt < 8; ++nt) {
    float bb = b1[nt * 16 + m];
#pragma unroll
    for (int r = 0; r < 4; ++r) {
      float v = fmaxf(acc[nt][r] + bb, 0.0f);
      hB[(mr + q * 4 + r) * H2S + nt * 16 + m] = f2b(v);
    }
  }
  __syncthreads();

  f32x4 ac2[8];
#pragma unroll
  for (int nt = 0; nt < 8; ++nt) ac2[nt] = (f32x4){0.f, 0.f, 0.f, 0.f};
  for (int ks = 0; ks < 4; ++ks) {
    bf16x8 a = *(const bf16x8*)&hB[(mr + m) * H2S + ks * 32 + q * 8];
#pragma unroll
    for (int nt = 0; nt < 8; ++nt) {
      bf16x8 b = *(const bf16x8*)&w2t[(size_t)(nt * 16 + m) * NF + ks * 32 + q * 8];
      ac2[nt] = __builtin_amdgcn_mfma_f32_16x16x32_bf16(a, b, ac2[nt], 0, 0, 0);
    }
  }
#pragma unroll
  for (int nt = 0; nt < 8; ++nt) {
    float bb = b2[nt * 16 + m];
#pragma unroll
    for (int r = 0; r < 4; ++r) {
      out[(size_t)(n0 + mr + q * 4 + r) * NF + nt * 16 + m] = fmaxf(ac2[nt][r] + bb, 0.0f);
    }
  }
}

extern "C" void kernel_launch(void* const* d_in, const int* in_sizes, int n_in,
                              void* d_out, int out_size, void* d_ws, size_t ws_size,
                              hipStream_t stream) {
  const float* edge_logits = (const float*)d_in[0];
  const float* edge_feats  = (const float*)d_in[1];
  const float* node_feats  = (const float*)d_in[2];
  const int*   dst         = (const int*)d_in[3];
  const float* W_et        = (const float*)d_in[4];
  const float* b_et        = (const float*)d_in[5];
  const float* W1          = (const float*)d_in[6];
  const float* b1          = (const float*)d_in[7];
  const float* W2          = (const float*)d_in[8];
  const float* b2          = (const float*)d_in[9];
  float* out = (float*)d_out;

  const int E = in_sizes[0];          // 1,600,000
  const int n = in_sizes[2] / NF;     // 100,000

  // ws layout
  unsigned* ctx = (unsigned*)d_ws;                     // n*8 u32 = n*16 bf16 accumulators
  float* denom  = (float*)(ctx + (size_t)n * 8);       // n f32
  unsigned short* w1t = (unsigned short*)(denom + n);  // 160*128 bf16
  unsigned short* w2t = w1t + NF * K1;                 // 128*128 bf16

  const int thr = 256;
  const int initN = n * 8;                             // covers ctx, denom, weights

  k_init<<<(initN + thr - 1) / thr, thr, 0, stream>>>(ctx, denom, n, W1, W2, w1t, w2t);
  k_edge<<<2048, thr, 0, stream>>>(dst, edge_logits, edge_feats, ctx, denom, E);
  k_node<<<(n + 63) / 64, 256, 0, stream>>>((const unsigned short*)ctx, denom, W_et, b_et,
                                            node_feats, w1t, w2t, b1, b2, out, n);
}

// Round 7
// 390.266 us; speedup vs baseline: 1.2568x; 1.0056x over previous
//
#include <hip/hip_runtime.h>

#define EF 16      // EDGE_FEAT
#define EH 32      // EDGE_HID
#define NF 128     // NODE_FEAT
#define K1 160     // EH + NF
#define HS 168     // LDS hA row stride (ushorts)
#define H2S 136    // LDS hB row stride (ushorts)
#define CW 16      // ctxd row stride in u32 (64B: 8 u32 bf16-pairs + 1 f32 denom + pad)

typedef __attribute__((ext_vector_type(8))) short bf16x8;
typedef __attribute__((ext_vector_type(4))) float f32x4;

__device__ __forceinline__ unsigned short f2b(float f) {  // fp32 -> bf16 RNE
  unsigned u = __float_as_uint(f);
  u += 0x7FFFu + ((u >> 16) & 1u);
  return (unsigned short)(u >> 16);
}
__device__ __forceinline__ unsigned pack2b(float a, float b) {  // [b|a] packed bf16
  return (unsigned)f2b(a) | ((unsigned)f2b(b) << 16);
}
// HW packed bf16x2 atomic add (gfx950 global_atomic_pk_add_bf16), fire-and-forget.
__device__ __forceinline__ void atom_pk_bf16(unsigned* addr, unsigned val) {
  asm volatile("global_atomic_pk_add_bf16 %0, %1, off" :: "v"(addr), "v"(val) : "memory");
}

// ---- init: zero interleaved ctx+denom rows + build bf16-transposed weights ----
__global__ void k_init(unsigned* __restrict__ ctxd, int n,
                       const float* __restrict__ W1, const float* __restrict__ W2,
                       unsigned short* __restrict__ w1t, unsigned short* __restrict__ w2t) {
  int i = blockIdx.x * blockDim.x + threadIdx.x;
  if (i < n * CW) ctxd[i] = 0u;         // n x 64B rows (ctx bf16x16 + denom f32 + pad)
  if (i < K1 * NF) {                    // w1t[nn][k] = W1[k][nn]
    int nn = i / K1, k = i % K1;
    w1t[i] = f2b(W1[k * NF + nn]);
  } else if (i < K1 * NF + NF * NF) {   // w2t[nn][k] = W2[k][nn]
    int j = i - K1 * NF;
    int nn = j / NF, k = j % NF;
    w2t[j] = f2b(W2[k * NF + nn]);
  }
}

// ---- single streaming pass over edges: segmented sum via HW atomics ----
// r5/r6 established: k_edge time scales with (edges x distinct 64B granules
// receiving atomics), not with op count (27.2M->14.4M ops changed nothing) and
// not with sector count (150->100MB changed nothing). Both rounds touched TWO
// granules per edge (ctx row + denom word) -> ~170us at ~53ns/granule.
// THIS ROUND: denom lives in the SAME 64B row as the ctx accumulators, so each
// edge's 8 pk-atomics + 1 f32 atomic hit ONE granule. Everything else identical.
__global__ __launch_bounds__(256) void k_edge(
    const int* __restrict__ dst, const float* __restrict__ logits,
    const float* __restrict__ efeat,
    unsigned* __restrict__ ctxd, int n_edges) {
  int gid = (int)((blockIdx.x * blockDim.x + threadIdx.x) >> 3);
  int c = threadIdx.x & 7;              // bf16-pair index (features 2c, 2c+1)
  int ngroups = (int)((gridDim.x * blockDim.x) >> 3);
#pragma unroll 2
  for (int e = gid; e < n_edges; e += ngroups) {
    int d = dst[e];                     // broadcast within group
    float ex = __expf(logits[e]);       // no max-shift: logits ~N(0,1), fp32-safe
    float2 f = *(const float2*)&efeat[(size_t)e * EF + c * 2];
    unsigned* row = &ctxd[(size_t)d * CW];
    atom_pk_bf16(row + c, pack2b(ex * f.x, ex * f.y));
    if (c == 0) unsafeAtomicAdd((float*)(row + 8), ex);   // same 64B granule
  }
}

// ---- per-node 2-layer MLP via bf16 MFMA, with fused context finisher ----
// Staging computes the 16->32 GEMV + normalize + bias + ELU from the bf16 ctx
// accumulators (interleaved row: 16 bf16 + f32 denom) directly into hA:
// c_j = (sum_k ctx_k * W_et[k][j]) / denom + b_et[j]  (denom==0 -> 0 -> elu(0)=0).
// 64 nodes/block, 4 waves; wave w owns node rows [w*16, w*16+16), full 128 cols.
// A layout (m89): A[m=lane&15][k=(lane>>4)*8+j]; C/D: row=(lane>>4)*4+reg, col=lane&15.
__global__ __launch_bounds__(256) void k_node(
    const unsigned* __restrict__ ctxd,
    const float* __restrict__ W_et, const float* __restrict__ b_et,
    const float* __restrict__ nf,
    const unsigned short* __restrict__ w1t, const unsigned short* __restrict__ w2t,
    const float* __restrict__ b1, const float* __restrict__ b2,
    float* __restrict__ out, int n_nodes) {
  __shared__ __align__(16) unsigned short hA[64 * HS];
  __shared__ __align__(16) unsigned short hB[64 * H2S];
  const int t = threadIdx.x;
  const int w = t >> 6, lane = t & 63;
  const int m = lane & 15, q = lane >> 4;
  int n0 = blockIdx.x * 64;
  if (n0 + 64 > n_nodes) n0 = n_nodes - 64;  // tail overlap: identical rewrites, benign

  // stage context: GEMV 16->32 + normalize + bias + ELU -> bf16. 8 outputs/thread.
  {
    int node = t >> 2, jg = (t & 3) * 8;
    const unsigned* row = &ctxd[(size_t)(n0 + node) * CW];
    float den = __uint_as_float(row[8]);
    float inv = (den > 0.0f) ? 1.0f / den : 0.0f;
    float S = (den > 0.0f) ? 1.0f : 0.0f;
    const unsigned short* cr = (const unsigned short*)row;
    float cf[EF];
#pragma unroll
    for (int k = 0; k < EF; ++k) cf[k] = __uint_as_float((unsigned)cr[k] << 16);
    unsigned short r[8];
#pragma unroll
    for (int jj = 0; jj < 8; ++jj) {
      int j = jg + jj;
      float acc = 0.0f;
#pragma unroll
      for (int k = 0; k < EF; ++k) acc += cf[k] * W_et[k * EH + j];
      float cv = acc * inv + S * b_et[j];
      float ctxv = (cv > 0.0f) ? cv : (__expf(cv) - 1.0f);
      r[jj] = f2b(ctxv);
    }
    *(uint4*)&hA[node * HS + jg] = *(const uint4*)r;
  }
  // stage node_feats fp32 -> bf16: 64x128, 8x float4/thread
#pragma unroll
  for (int i = 0; i < 8; ++i) {
    int idx = t + 256 * i;
    int node = idx >> 5, j = (idx & 31) * 4;
    float4 v = *(const float4*)&nf[(size_t)(n0 + node) * NF + j];
    unsigned short r[4] = {f2b(v.x), f2b(v.y), f2b(v.z), f2b(v.w)};
    *(uint2*)&hA[node * HS + EH + j] = *(const uint2*)r;
  }
  __syncthreads();

  const int mr = w * 16;
  f32x4 acc[8];
#pragma unroll
  for (int nt = 0; nt < 8; ++nt) acc[nt] = (f32x4){0.f, 0.f, 0.f, 0.f};
  for (int ks = 0; ks < 5; ++ks) {
    bf16x8 a = *(const bf16x8*)&hA[(mr + m) * HS + ks * 32 + q * 8];
#pragma unroll
    for (int nt = 0; nt < 8; ++nt) {
      bf16x8 b = *(const bf16x8*)&w1t[(size_t)(nt * 16 + m) * K1 + ks * 32 + q * 8];
      acc[nt] = __builtin_amdgcn_mfma_f32_16x16x32_bf16(a, b, acc[nt], 0, 0, 0);
    }
  }
  // epilogue 1: bias + relu -> hB (bf16), wave-private rows
#pragma unroll
  for (int nt = 0; nt < 8; ++nt) {
    float bb = b1[nt * 16 + m];
#pragma unroll
    for (int r = 0; r < 4; ++r) {
      float v = fmaxf(acc[nt][r] + bb, 0.0f);
      hB[(mr + q * 4 + r) * H2S + nt * 16 + m] = f2b(v);
    }
  }
  __syncthreads();

  f32x4 ac2[8];
#pragma unroll
  for (int nt = 0; nt < 8; ++nt) ac2[nt] = (f32x4){0.f, 0.f, 0.f, 0.f};
  for (int ks = 0; ks < 4; ++ks) {
    bf16x8 a = *(const bf16x8*)&hB[(mr + m) * H2S + ks * 32 + q * 8];
#pragma unroll
    for (int nt = 0; nt < 8; ++nt) {
      bf16x8 b = *(const bf16x8*)&w2t[(size_t)(nt * 16 + m) * NF + ks * 32 + q * 8];
      ac2[nt] = __builtin_amdgcn_mfma_f32_16x16x32_bf16(a, b, ac2[nt], 0, 0, 0);
    }
  }
#pragma unroll
  for (int nt = 0; nt < 8; ++nt) {
    float bb = b2[nt * 16 + m];
#pragma unroll
    for (int r = 0; r < 4; ++r) {
      out[(size_t)(n0 + mr + q * 4 + r) * NF + nt * 16 + m] = fmaxf(ac2[nt][r] + bb, 0.0f);
    }
  }
}

extern "C" void kernel_launch(void* const* d_in, const int* in_sizes, int n_in,
                              void* d_out, int out_size, void* d_ws, size_t ws_size,
                              hipStream_t stream) {
  const float* edge_logits = (const float*)d_in[0];
  const float* edge_feats  = (const float*)d_in[1];
  const float* node_feats  = (const float*)d_in[2];
  const int*   dst         = (const int*)d_in[3];
  const float* W_et        = (const float*)d_in[4];
  const float* b_et        = (const float*)d_in[5];
  const float* W1          = (const float*)d_in[6];
  const float* b1          = (const float*)d_in[7];
  const float* W2          = (const float*)d_in[8];
  const float* b2          = (const float*)d_in[9];
  float* out = (float*)d_out;

  const int E = in_sizes[0];          // 1,600,000
  const int n = in_sizes[2] / NF;     // 100,000

  // ws layout (64B-align ctxd so each row is one 64B granule / half a 128B line)
  unsigned* ctxd = (unsigned*)(((uintptr_t)d_ws + 63) & ~(uintptr_t)63);  // n*CW u32
  unsigned short* w1t = (unsigned short*)(ctxd + (size_t)n * CW);  // 160*128 bf16
  unsigned short* w2t = w1t + NF * K1;                             // 128*128 bf16

  const int thr = 256;
  const int initN = n * CW;                            // covers ctxd + weights

  k_init<<<(initN + thr - 1) / thr, thr, 0, stream>>>(ctxd, n, W1, W2, w1t, w2t);
  k_edge<<<2048, thr, 0, stream>>>(dst, edge_logits, edge_feats, ctxd, E);
  k_node<<<(n + 63) / 64, 256, 0, stream>>>(ctxd, W_et, b_et, node_feats,
                                            w1t, w2t, b1, b2, out, n);
}